// Round 12
// baseline (112.292 us; speedup 1.0000x reference)
//
#include <hip/hip_runtime.h>
#include <hip/hip_bf16.h>

#define NL    64
#define DIN   512
#define DOUT  512
#define BATCH 1024

#define BM 128
#define BN 128
#define BK 64
#define NKS (DIN / BK)   // 8

typedef short short8 __attribute__((ext_vector_type(8)));
typedef float f32x4  __attribute__((ext_vector_type(4)));

__device__ __forceinline__ unsigned int pk2(float a, float b) {
    // v_cvt_pk_bf16_f32 (RNE)
    __hip_bfloat162 h = __float22bfloat162_rn(make_float2(a, b));
    unsigned int r;
    __builtin_memcpy(&r, &h, 4);
    return r;
}

// ---- pre-pass: w fp32 [l][k][c] -> bf16 wt [l][c][k], 16B-slot swizzled ----
// Within each 128B k-group of a col: logical slot s stored at s ^ (c & 7).
__global__ __launch_bounds__(256) void wcvt_kernel(
        const float* __restrict__ w, unsigned short* __restrict__ wt) {
    __shared__ float T[64][65];
    const int tid = threadIdx.x;
    const int b   = blockIdx.x;
    const int l   = b >> 6;
    const int kg  = (b >> 3) & 7;   // 64-k group
    const int cg  = b & 7;          // 64-col group

    const float* src = w + ((size_t)(l * DIN) + kg * 64) * DOUT + cg * 64;
    const int j0 = (tid & 15) * 4;
    const int i0 = tid >> 4;
#pragma unroll
    for (int p = 0; p < 4; ++p) {
        const int i = p * 16 + i0;
        f32x4 v = *reinterpret_cast<const f32x4*>(src + (size_t)i * DOUT + j0);
        T[i][j0] = v[0]; T[i][j0 + 1] = v[1];
        T[i][j0 + 2] = v[2]; T[i][j0 + 3] = v[3];
    }
    __syncthreads();

    const int cl   = tid >> 2;      // 0..63
    const int part = tid & 3;       // 0..3 (16 k each = 2 slots)
    const int col  = cg * 64 + cl;
    float v[16];
#pragma unroll
    for (int q = 0; q < 16; ++q) v[q] = T[part * 16 + q][cl];
    uint4 u0, u1;
    u0.x = pk2(v[0], v[1]);  u0.y = pk2(v[2], v[3]);
    u0.z = pk2(v[4], v[5]);  u0.w = pk2(v[6], v[7]);
    u1.x = pk2(v[8], v[9]);  u1.y = pk2(v[10], v[11]);
    u1.z = pk2(v[12], v[13]); u1.w = pk2(v[14], v[15]);
    unsigned short* ob = wt + ((size_t)(l * DOUT) + col) * DIN + kg * 64;
    const int key = col & 7;
    *reinterpret_cast<uint4*>(ob + (((part * 2)     ^ key) << 3)) = u0;
    *reinterpret_cast<uint4*>(ob + (((part * 2 + 1) ^ key) << 3)) = u1;
}

// ---- GEMM: A fp32 via global_load_lds (pre-swizzled src), B bf16 from wt ----
__global__ __launch_bounds__(256, 3) void nlinear_gemm(
        const float* __restrict__ x, const unsigned short* __restrict__ wt,
        const float* __restrict__ bias, float* __restrict__ out) {
    // A: fp32 [128][64], 256B rows = 16 slots, key = ((r&7)<<1)|((r>>3)&1)
    // B: bf16 [128][64], 128B rows = 8 slots,  key = col&7 (pre-swizzled in wt)
    __shared__ float          As[BM * BK];   // 32 KB
    __shared__ unsigned short Bs[BN * BK];   // 16 KB

    const int tid = threadIdx.x;
    const int bid = blockIdx.x;
    // XCD swizzle: 2048 = 8 XCDs x 256 blocks; each XCD owns 8 whole layers
    const int nb    = (bid & 7) * 256 + (bid >> 3);
    const int layer = nb >> 5;
    const int tile  = nb & 31;
    const int bm0   = (tile >> 2) * BM;
    const int bn0   = (tile & 3) * BN;

    const int wid  = tid >> 6;
    const int lane = tid & 63;
    const int wr   = wid >> 1, wc = wid & 1;   // 2x2 waves, 64x64 each
    const int lrow = lane & 15;
    const int lkb  = lane >> 4;

    // A staging: instr i covers rows i*16 + (tid>>4); slot p = tid&15
    const int rowA = tid >> 4;
    const int pA   = tid & 15;
    const int akey = ((rowA & 7) << 1) | ((rowA >> 3) & 1);  // const per thread
    // B staging: instr i covers cols i*32 + (tid>>3); slot s = tid&7
    const int colB = tid >> 3;
    const int sB   = tid & 7;

    const size_t XS = (size_t)NL * DIN;
    const float* xb = x + (size_t)bm0 * XS + (size_t)layer * DIN;
    const float* asrc0 = xb + (size_t)rowA * XS + ((pA ^ akey) << 2);
    const unsigned short* bsrc0 =
        wt + ((size_t)(layer * DOUT) + bn0 + colB) * DIN + sB * 8;

    f32x4 acc[4][4];
#pragma unroll
    for (int i = 0; i < 4; ++i)
#pragma unroll
        for (int j = 0; j < 4; ++j) acc[i][j] = (f32x4){0.f, 0.f, 0.f, 0.f};

#pragma unroll 1
    for (int ks = 0; ks < NKS; ++ks) {
        const int k0 = ks * BK;
        // ---- stage A: 8x global_load_lds_dwordx4 (fp32, swizzled source) ----
#pragma unroll
        for (int i = 0; i < 8; ++i) {
            const float* g = asrc0 + (size_t)(i * 16) * XS + k0;
            __builtin_amdgcn_global_load_lds(
                (const __attribute__((address_space(1))) unsigned int*)g,
                (__attribute__((address_space(3))) unsigned int*)
                    ((char*)As + i * 4096 + tid * 16),
                16, 0, 0);
        }
        // ---- stage B: 4x global_load_lds_dwordx4 (bf16, memory pre-swizzled) ----
#pragma unroll
        for (int i = 0; i < 4; ++i) {
            const unsigned short* g = bsrc0 + (size_t)(i * 32) * DIN + k0;
            __builtin_amdgcn_global_load_lds(
                (const __attribute__((address_space(1))) unsigned int*)g,
                (__attribute__((address_space(3))) unsigned int*)
                    ((char*)Bs + i * 4096 + tid * 16),
                16, 0, 0);
        }
        __syncthreads();   // drains vmcnt: tile visible

        // ---- compute: 2 k-slices x 16 MFMA; A cvt at register edge ----
#pragma unroll
        for (int kk = 0; kk < 2; ++kk) {
            short8 af[4], bf[4];
#pragma unroll
            for (int mi = 0; mi < 4; ++mi) {
                const int row = wr * 64 + mi * 16 + lrow;
                const int key = ((row & 7) << 1) | ((row >> 3) & 1);
                const int sg  = kk * 8 + lkb * 2;
                const float* rp = &As[row * BK];
                f32x4 v0 = *reinterpret_cast<const f32x4*>(rp + ((sg ^ key) << 2));
                f32x4 v1 = *reinterpret_cast<const f32x4*>(rp + (((sg + 1) ^ key) << 2));
                uint4 u;
                u.x = pk2(v0[0], v0[1]); u.y = pk2(v0[2], v0[3]);
                u.z = pk2(v1[0], v1[1]); u.w = pk2(v1[2], v1[3]);
                __builtin_memcpy(&af[mi], &u, 16);
            }
#pragma unroll
            for (int ni = 0; ni < 4; ++ni) {
                const int col = wc * 64 + ni * 16 + lrow;
                const int pos = (kk * 4 + lkb) ^ (col & 7);
                bf[ni] = *reinterpret_cast<const short8*>(&Bs[col * BK + (pos << 3)]);
            }
#pragma unroll
            for (int mi = 0; mi < 4; ++mi)
#pragma unroll
                for (int ni = 0; ni < 4; ++ni)
                    acc[mi][ni] = __builtin_amdgcn_mfma_f32_16x16x32_bf16(
                        af[mi], bf[ni], acc[mi][ni], 0, 0, 0);
        }
        __syncthreads();   // reads done before next stage overwrites
    }

    // ---- epilogue: + bias, fp32 store ----
    const float* bb = bias + (size_t)layer * DOUT + bn0;
    float* ob = out + (size_t)bm0 * (NL * DOUT) + (size_t)layer * DOUT + bn0;
#pragma unroll
    for (int mi = 0; mi < 4; ++mi) {
#pragma unroll
        for (int ni = 0; ni < 4; ++ni) {
            const int col = wc * 64 + ni * 16 + lrow;
            const float bval = bb[col];
#pragma unroll
            for (int r = 0; r < 4; ++r) {
                const int row = wr * 64 + mi * 16 + lkb * 4 + r;
                ob[(size_t)row * (NL * DOUT) + col] = acc[mi][ni][r] + bval;
            }
        }
    }
}

extern "C" void kernel_launch(void* const* d_in, const int* in_sizes, int n_in,
                              void* d_out, int out_size, void* d_ws, size_t ws_size,
                              hipStream_t stream) {
    const float* x  = (const float*)d_in[0];
    const float* w  = (const float*)d_in[1];
    const float* b  = (const float*)d_in[2];
    float* out      = (float*)d_out;
    unsigned short* wt = (unsigned short*)d_ws;   // 64*512*512*2 = 33.5 MB

    hipLaunchKernelGGL(wcvt_kernel, dim3(NL * 8 * 8), dim3(256), 0, stream, w, wt);
    hipLaunchKernelGGL(nlinear_gemm, dim3(NL * (BATCH / BM) * (DOUT / BN)),
                       dim3(256), 0, stream, x, wt, b, out);
}